// Round 21
// baseline (350.625 us; speedup 1.0000x reference)
//
#include <hip/hip_runtime.h>
#include <math.h>

#define NPATH 23
#define NEDGE 50000
#define NCHAN 32
#define NWROW 736      // 23*32 weight row length
#define OUTW  99       // concatenated output width
#define EPB   4        // edges per block (swept: 2->277, 4->251, 8->258 us)
#define NTHR  512
#define NBLK  (NEDGE/EPB)   // 12500
#define TSZ   632      // padded T slots per edge
#define OBW   100      // obuf row width in halfs (pad col 99 -> 4B-aligned rows)

// Path tables (derived from the reference's _build_paths; verified rounds 0-20)
constexpr int L1[NPATH]    = {0,0,0,0,1,1,1,1,1,1,2,2,2,2,2,2,2,3,3,3,3,3,3};
constexpr int L2[NPATH]    = {0,1,2,3,0,1,1,2,2,3,0,1,1,2,2,3,3,0,1,2,2,3,3};
constexpr int L3[NPATH]    = {0,1,2,3,1,0,2,1,3,2,2,1,3,0,2,1,3,3,2,1,3,0,2};
constexpr int POS[NPATH]   = {0,4,10,17,5,1,11,6,18,12,13,7,19,2,14,8,20,21,15,9,22,3,16};
constexpr int OOFF[NPATH]  = {0,4,7,12,19,1,34,22,39,46,51,31,61,2,73,25,78,85,68,28,92,3,56};
constexpr int LOFF[4]      = {0,1,4,9};

constexpr int PAD(int n1){ return n1 <= 3 ? 4 : 8; }
struct PT { int v[NPATH]; int total; };
constexpr PT make_ptoff(){
    PT t{}; int a = 0;
    for(int p = 0; p < NPATH; ++p){ t.v[p] = a; a += (2*L3[p]+1)*PAD(2*L1[p]+1); }
    t.total = a;
    return t;
}
constexpr PT PTOF = make_ptoff();
static_assert(PTOF.total == TSZ, "padded T size");

// 4-way path split (FMA 114/112/105/108). Group 3 split into two 5-path
// register sub-phases (masks OR to 0x182EF). Proven R13-R15.
#define G0M  0xE0010u
#define G1M  0x700100u
#define G2M  0x7C00u
#define G3LO 0x2Fu      // paths 0,1,2,3,5
#define G3HI 0x182C0u   // paths 6,7,9,15,16

typedef _Float16 __attribute__((ext_vector_type(4))) h4;

__device__ __forceinline__ int imx(int a, int b){ return a > b ? a : b; }
__device__ __forceinline__ int imn(int a, int b){ return a < b ? a : b; }

__device__ __forceinline__ double factd(int n){
    double r = 1.0;
    for(int i = 2; i <= n; ++i) r *= (double)i;
    return r;
}

// ---------------------------------------------------------------------------
// Setup: reference-exact _wigner_3j, emitting the CG table in PADDED-SLOT
// order cgd2p[632][16] (zero rows in pads). Verified R12/R19 (absmax 0.25).
// ---------------------------------------------------------------------------
__global__ __launch_bounds__(512) void cg_setup(float* __restrict__ cgd2p){
    const int p  = blockIdx.x;
    const int j1 = L1[p], j2 = L2[p], j3 = L3[p];
    const int n1 = 2*j1+1, n2 = 2*j2+1, n3 = 2*j3+1;
    const int o2 = LOFF[j2];
    const int ntot = n1*n2*n3;
    const int t = threadIdx.x;

    __shared__ double scg[343];
    __shared__ double qre[3][49];
    __shared__ double qim[3][49];
    __shared__ double red[512];

    if(t < ntot){
        int a   = t / (n2*n3);
        int rem = t - a*(n2*n3);
        int b   = rem / n3;
        int g   = rem - b*n3;
        int m1 = a - j1, m2 = b - j2, m3 = g - j3;
        double val = 0.0;
        if(m1 + m2 == m3){
            int vmin = imx(imx(-j1 + j2 + m3, -j1 + m1), 0);
            int vmax = imn(imn(j2 + j3 + m1, j3 - j1 + j2), j3 + m3);
            double C = sqrt((2.0*j3 + 1.0) * factd(j3 + j1 - j2) * factd(j3 - j1 + j2)
                            * factd(j1 + j2 - j3) / factd(j1 + j2 + j3 + 1));
            C *= sqrt(factd(j3 + m3) * factd(j3 - m3) * factd(j1 - m1)
                      * factd(j1 + m1) * factd(j2 - m2) * factd(j2 + m2));
            double S = 0.0;
            for(int v = vmin; v <= vmax; ++v){
                double sgn = ((v + j2 + m2) & 1) ? -1.0 : 1.0;
                S += sgn * factd(j2 + j3 + m1 - v) * factd(j1 - m1 + v)
                     / (factd(v) * factd(j3 - j1 + j2 - v) * factd(j3 + m3 - v)
                        * factd(v + j1 - j2 - m3));
            }
            val = C * S;
        }
        scg[t] = val;
    }

    if(t < 3){
        int l = (t == 0) ? j1 : ((t == 1) ? j2 : j3);
        int n = 2*l + 1;
        double* QR = qre[t];
        double* QI = qim[t];
        for(int i = 0; i < 49; ++i){ QR[i] = 0.0; QI[i] = 0.0; }
        const double is2 = 0.70710678118654752440;
        for(int m = -l; m < 0; ++m){
            QR[(l+m)*n + (l-m)] = is2;
            QI[(l+m)*n + (l+m)] = -is2;
        }
        QR[l*n + l] = 1.0;
        for(int m = 1; m <= l; ++m){
            double s = (m & 1) ? -1.0 : 1.0;
            QR[(l+m)*n + (l+m)] = s * is2;
            QI[(l+m)*n + (l-m)] = s * is2;
        }
        double fr, fi;
        switch(l & 3){
            case 0: fr = 1.0;  fi = 0.0;  break;
            case 1: fr = 0.0;  fi = -1.0; break;
            case 2: fr = -1.0; fi = 0.0;  break;
            default: fr = 0.0; fi = 1.0;  break;
        }
        for(int i = 0; i < n*n; ++i){
            double re = QR[i], im = QI[i];
            QR[i] = re*fr - im*fi;
            QI[i] = re*fi + im*fr;
        }
    }
    __syncthreads();

    double val = 0.0;
    if(t < ntot){
        int j   = t / (n2*n3);
        int rem = t - j*(n2*n3);
        int lq  = rem / n3;
        int m   = rem - lq*n3;
        double acc = 0.0;
        for(int i = 0; i < n1; ++i){
            double q1r = qre[0][i*n1 + j], q1i = qim[0][i*n1 + j];
            if(q1r == 0.0 && q1i == 0.0) continue;
            for(int k = 0; k < n2; ++k){
                double q2r = qre[1][k*n2 + lq], q2i = qim[1][k*n2 + lq];
                if(q2r == 0.0 && q2i == 0.0) continue;
                double ar = q1r*q2r - q1i*q2i;
                double ai = q1r*q2i + q1i*q2r;
                for(int n = 0; n < n3; ++n){
                    double cv = scg[(i*n2 + k)*n3 + n];
                    if(cv == 0.0) continue;
                    double q3r = qre[2][n*n3 + m];
                    double q3i = -qim[2][n*n3 + m];
                    acc += cv * (ar*q3r - ai*q3i);
                }
            }
        }
        val = acc;
    }

    red[t] = val * val;
    __syncthreads();
    if(t < 343) scg[t] = val;
    for(int s2 = 256; s2 > 0; s2 >>= 1){
        if(t < s2) red[t] += red[t + s2];
        __syncthreads();
    }
    const double scale = sqrt(2.0*j3 + 1.0) / sqrt(red[0]);

    const int padn = PAD(n1);
    const int sh   = (padn == 8) ? 3 : 2;
    for(int u = t; u < n3*padn*16; u += 512){
        int row = u >> 4;
        int jf  = u & 15;
        int k   = row >> sh;
        int ip  = row & (padn - 1);
        int j   = jf - o2;
        double v2 = (ip < n1 && j >= 0 && j < n2) ? scg[(ip*n2 + j)*n3 + k] : 0.0;
        cgd2p[(size_t)(PTOF.v[p] + row)*16 + jf] = (float)(v2 * scale);
    }
}

// ---------------------------------------------------------------------------
// w prefetch templated on a compile-time path MASK (<=5 entries per mask).
// ---------------------------------------------------------------------------
template<unsigned MASK>
__device__ __forceinline__ void prefetchW(const float* __restrict__ wbase,
                                          float* __restrict__ wreg)
{
    #pragma unroll
    for(int p = 0; p < NPATH; ++p){
        if((MASK >> p) & 1u)
            wreg[__builtin_popcount(MASK & ((1u << p) - 1u))] = wbase[POS[p]*NCHAN];
    }
}

// ---------------------------------------------------------------------------
// Phase C (low-LDS-instruction variant, R10-verified): padded k-major T
// layout -> 1-2 float4 LDS reads per k-row (vs n1 scalar); fp16 pair-packed
// obuf writes into 4B-aligned padded rows (vs scalar b16).
// ---------------------------------------------------------------------------
template<unsigned MASK>
__device__ __forceinline__ void phaseCp(const float* __restrict__ xr,
                                        const float* __restrict__ wreg,
                                        const float* __restrict__ Te,
                                        _Float16* __restrict__ ob)
{
    #pragma unroll
    for(int p = 0; p < NPATH; ++p){
        if(!((MASK >> p) & 1u)) continue;          // folds after unroll
        const int widx = __builtin_popcount(MASK & ((1u << p) - 1u));
        const int n1  = 2*L1[p] + 1;
        const int n3  = 2*L3[p] + 1;
        const int o1  = LOFF[L1[p]];
        const int pad = PAD(n1);
        const float wp = wreg[widx];

        float acc[7];
        #pragma unroll
        for(int k = 0; k < n3; ++k){
            const float* tr = Te + PTOF.v[p] + k*pad;
            float4 t0 = *(const float4*)tr;
            float a = xr[o1] * t0.x;
            if(n1 > 1){
                a = fmaf(xr[o1+1], t0.y, a);
                a = fmaf(xr[o1+2], t0.z, a);
            }
            if(n1 > 3){
                a = fmaf(xr[o1+3], t0.w, a);
                float4 t1 = *((const float4*)tr + 1);
                a = fmaf(xr[o1+4], t1.x, a);
                if(n1 > 5){
                    a = fmaf(xr[o1+5], t1.y, a);
                    a = fmaf(xr[o1+6], t1.z, a);
                }
            }
            acc[k] = a * wp;
        }

        // pack-store: optional lead half, b32 pairs, optional tail half
        const int off  = OOFF[p];
        const int lead = off & 1;
        if(lead) ob[off] = (_Float16)acc[0];
        const int npair = (n3 - lead) >> 1;
        #pragma unroll
        for(int kk = 0; kk < npair; ++kk){
            const int k0 = lead + 2*kk;
            _Float16 h0 = (_Float16)acc[k0];
            _Float16 h1 = (_Float16)acc[k0+1];
            unsigned u = (unsigned)__builtin_bit_cast(unsigned short, h0)
                       | ((unsigned)__builtin_bit_cast(unsigned short, h1) << 16);
            *reinterpret_cast<unsigned*>(
                reinterpret_cast<char*>(ob) + (size_t)(off + k0)*2) = u;
        }
        if((n3 - lead) & 1) ob[off + n3 - 1] = (_Float16)acc[n3-1];
    }
}

// ---------------------------------------------------------------------------
// Main kernel: R15 shell (EPB=4, 512 thr, 3 barriers, 4 blocks/CU) with the
// R10 low-LDS-instruction phase C. Wave = (path group, edge half). x issued
// after barrier 1; <=5 w regs; group-3 5+5 split. obuf rows padded to 100
// halfs; flush skips the pad (R10-proven exact WRITE_SIZE).
// LDS = 25.6 + 10.1 + 0.25 KB ~ 36 KB -> 4 blocks/CU = 32 waves/CU.
// ---------------------------------------------------------------------------
__global__ __launch_bounds__(NTHR, 8) void tp_main(
    const float* __restrict__ x, const float* __restrict__ y,
    const float* __restrict__ w, const float* __restrict__ cgd2p,
    float* __restrict__ out)
{
    __shared__ __align__(16) _Float16 obuf[EPB*NCHAN*OBW];  // 12800 h, 25.6 KB
    __shared__ __align__(16) float Ts[EPB*TSZ];             // 2528 f, 10.1 KB
    __shared__ float ys[EPB*16];

    const int tid = threadIdx.x;
    const int e0  = blockIdx.x * EPB;

    const int lane = tid & 63;
    const int wid  = tid >> 6;
    const int c    = lane & 31;                          // channel
    const int grp  = wid & 3;                            // path group (0..3)
    const int el   = ((wid >> 2) << 1) | (lane >> 5);    // edge in block (0..3)
    const int e    = e0 + el;

    // prefetch this group's w values (<=5 registers, cheap to hold)
    const float* wbase = w + (size_t)e*NWROW + c;
    float wreg[5];
    switch(grp){
        case 0: prefetchW<G0M>(wbase, wreg); break;
        case 1: prefetchW<G1M>(wbase, wreg); break;
        case 2: prefetchW<G2M>(wbase, wreg); break;
        default: prefetchW<G3LO>(wbase, wreg); break;
    }

    if(tid < EPB*16) ys[tid] = y[e0*16 + tid];
    __syncthreads();                                   // barrier 1

    // issue x loads NOW — latency covered by phase B, consumed in phase C;
    // does not live across barrier 1 (register-pressure discipline, R14).
    const float4* xp = reinterpret_cast<const float4*>(x + (size_t)(e*NCHAN + c)*16);
    float4 x0 = xp[0], x1 = xp[1], x2 = xp[2], x3 = xp[3];

    // Phase B: T over PADDED slots (zero CG rows in pads -> T=0 there)
    for(int u = tid; u < EPB*TSZ; u += NTHR){
        int eli = u / TSZ;
        int s   = u - eli*TSZ;
        const float* cr = cgd2p + (size_t)s*16;
        float acc = 0.f;
        #pragma unroll
        for(int j = 0; j < 16; ++j)
            acc = fmaf(ys[eli*16 + j], cr[j], acc);
        Ts[u] = acc;
    }
    __syncthreads();                                   // barrier 2

    // Phase C: straight-line per-wave path group (b128 T reads, packed writes)
    float xr[16];
    xr[0]=x0.x;  xr[1]=x0.y;  xr[2]=x0.z;  xr[3]=x0.w;
    xr[4]=x1.x;  xr[5]=x1.y;  xr[6]=x1.z;  xr[7]=x1.w;
    xr[8]=x2.x;  xr[9]=x2.y;  xr[10]=x2.z; xr[11]=x2.w;
    xr[12]=x3.x; xr[13]=x3.y; xr[14]=x3.z; xr[15]=x3.w;

    const float* Te = Ts + el*TSZ;
    _Float16* ob = obuf + (el*NCHAN + c)*OBW;

    switch(grp){
        case 0: phaseCp<G0M>(xr, wreg, Te, ob); break;
        case 1: phaseCp<G1M>(xr, wreg, Te, ob); break;
        case 2: phaseCp<G2M>(xr, wreg, Te, ob); break;
        default: {
            float wregB[5];
            prefetchW<G3HI>(wbase, wregB);      // issued early; waited on
            phaseCp<G3LO>(xr, wreg, Te, ob);    //   under this compute
            phaseCp<G3HI>(xr, wregB, Te, ob);
            break;
        }
    }
    __syncthreads();                                   // barrier 3

    // Flush: 3200 h4 chunks; skip the per-row pad half (col 99).
    // R10-proven: dword stores, full line coverage, exact WRITE_SIZE.
    const h4* ob4 = reinterpret_cast<const h4*>(obuf);
    float* outb = out + (size_t)blockIdx.x * (EPB*NCHAN*OUTW);
    for(int idx = tid; idx < EPB*NCHAN*25; idx += NTHR){
        int row = idx / 25;             // el*32 + c
        int j   = idx - row*25;
        h4 hv = ob4[idx];
        float* base = outb + (size_t)row*OUTW + 4*j;
        base[0] = (float)hv[0];
        base[1] = (float)hv[1];
        base[2] = (float)hv[2];
        if(j < 24) base[3] = (float)hv[3];
    }
}

extern "C" void kernel_launch(void* const* d_in, const int* in_sizes, int n_in,
                              void* d_out, int out_size, void* d_ws, size_t ws_size,
                              hipStream_t stream)
{
    const float* x  = (const float*)d_in[0];
    const float* y  = (const float*)d_in[1];
    const float* wt = (const float*)d_in[2];
    float* out = (float*)d_out;
    float* cgd2p = (float*)d_ws;   // 632*16 floats = 40.4 KB of scratch

    cg_setup<<<NPATH, 512, 0, stream>>>(cgd2p);
    tp_main<<<NBLK, NTHR, 0, stream>>>(x, y, wt, cgd2p, out);
}

// Round 22
// 250.335 us; speedup vs baseline: 1.4006x; 1.4006x over previous
//
#include <hip/hip_runtime.h>
#include <math.h>

#define NPATH 23
#define NEDGE 50000
#define NCHAN 32
#define NWROW 736      // 23*32 weight row length
#define OUTW  99       // concatenated output width
#define TTOT  439      // total T = sum n1*n3
#define EPB   4        // edges per block (swept: 2->277, 4->251, 8->258 us)
#define NTHR  512
#define NBLK  (NEDGE/EPB)   // 12500

// Path tables (derived from the reference's _build_paths; verified rounds 0-21)
constexpr int L1[NPATH]    = {0,0,0,0,1,1,1,1,1,1,2,2,2,2,2,2,2,3,3,3,3,3,3};
constexpr int L2[NPATH]    = {0,1,2,3,0,1,1,2,2,3,0,1,1,2,2,3,3,0,1,2,2,3,3};
constexpr int L3[NPATH]    = {0,1,2,3,1,0,2,1,3,2,2,1,3,0,2,1,3,3,2,1,3,0,2};
constexpr int POS[NPATH]   = {0,4,10,17,5,1,11,6,18,12,13,7,19,2,14,8,20,21,15,9,22,3,16};
constexpr int OOFF[NPATH]  = {0,4,7,12,19,1,34,22,39,46,51,31,61,2,73,25,78,85,68,28,92,3,56};
constexpr int TOFF[NPATH]  = {0,1,4,9,16,25,28,43,52,73,88,113,128,163,168,193,208,243,292,327,348,397,404};
constexpr int LOFF[4]      = {0,1,4,9};

// 4-way path split (FMA 114/112/105/108). Group 3 split into two 5-path
// register sub-phases (masks OR to 0x182EF).
#define G0M  0xE0010u
#define G1M  0x700100u
#define G2M  0x7C00u
#define G3LO 0x2Fu      // paths 0,1,2,3,5
#define G3HI 0x182C0u   // paths 6,7,9,15,16

typedef _Float16 __attribute__((ext_vector_type(4))) h4;

__device__ __forceinline__ int imx(int a, int b){ return a > b ? a : b; }
__device__ __forceinline__ int imn(int a, int b){ return a < b ? a : b; }

__device__ __forceinline__ double factd(int n){
    double r = 1.0;
    for(int i = 2; i <= n; ++i) r *= (double)i;
    return r;
}

// ---------------------------------------------------------------------------
// Setup: reference-exact _wigner_3j (verified R0/R6), emitting the DENSE
// [439 slots][16 jfull] fp32 matrix cgd2.
// ---------------------------------------------------------------------------
__global__ __launch_bounds__(512) void cg_setup(float* __restrict__ cgd2){
    const int p  = blockIdx.x;
    const int j1 = L1[p], j2 = L2[p], j3 = L3[p];
    const int n1 = 2*j1+1, n2 = 2*j2+1, n3 = 2*j3+1;
    const int o2 = LOFF[j2];
    const int ntot = n1*n2*n3;
    const int t = threadIdx.x;

    __shared__ double scg[343];
    __shared__ double qre[3][49];
    __shared__ double qim[3][49];
    __shared__ double red[512];

    if(t < ntot){
        int a   = t / (n2*n3);
        int rem = t - a*(n2*n3);
        int b   = rem / n3;
        int g   = rem - b*n3;
        int m1 = a - j1, m2 = b - j2, m3 = g - j3;
        double val = 0.0;
        if(m1 + m2 == m3){
            int vmin = imx(imx(-j1 + j2 + m3, -j1 + m1), 0);
            int vmax = imn(imn(j2 + j3 + m1, j3 - j1 + j2), j3 + m3);
            double C = sqrt((2.0*j3 + 1.0) * factd(j3 + j1 - j2) * factd(j3 - j1 + j2)
                            * factd(j1 + j2 - j3) / factd(j1 + j2 + j3 + 1));
            C *= sqrt(factd(j3 + m3) * factd(j3 - m3) * factd(j1 - m1)
                      * factd(j1 + m1) * factd(j2 - m2) * factd(j2 + m2));
            double S = 0.0;
            for(int v = vmin; v <= vmax; ++v){
                double sgn = ((v + j2 + m2) & 1) ? -1.0 : 1.0;
                S += sgn * factd(j2 + j3 + m1 - v) * factd(j1 - m1 + v)
                     / (factd(v) * factd(j3 - j1 + j2 - v) * factd(j3 + m3 - v)
                        * factd(v + j1 - j2 - m3));
            }
            val = C * S;
        }
        scg[t] = val;
    }

    if(t < 3){
        int l = (t == 0) ? j1 : ((t == 1) ? j2 : j3);
        int n = 2*l + 1;
        double* QR = qre[t];
        double* QI = qim[t];
        for(int i = 0; i < 49; ++i){ QR[i] = 0.0; QI[i] = 0.0; }
        const double is2 = 0.70710678118654752440;
        for(int m = -l; m < 0; ++m){
            QR[(l+m)*n + (l-m)] = is2;
            QI[(l+m)*n + (l+m)] = -is2;
        }
        QR[l*n + l] = 1.0;
        for(int m = 1; m <= l; ++m){
            double s = (m & 1) ? -1.0 : 1.0;
            QR[(l+m)*n + (l+m)] = s * is2;
            QI[(l+m)*n + (l-m)] = s * is2;
        }
        double fr, fi;
        switch(l & 3){
            case 0: fr = 1.0;  fi = 0.0;  break;
            case 1: fr = 0.0;  fi = -1.0; break;
            case 2: fr = -1.0; fi = 0.0;  break;
            default: fr = 0.0; fi = 1.0;  break;
        }
        for(int i = 0; i < n*n; ++i){
            double re = QR[i], im = QI[i];
            QR[i] = re*fr - im*fi;
            QI[i] = re*fi + im*fr;
        }
    }
    __syncthreads();

    double val = 0.0;
    if(t < ntot){
        int j   = t / (n2*n3);
        int rem = t - j*(n2*n3);
        int lq  = rem / n3;
        int m   = rem - lq*n3;
        double acc = 0.0;
        for(int i = 0; i < n1; ++i){
            double q1r = qre[0][i*n1 + j], q1i = qim[0][i*n1 + j];
            if(q1r == 0.0 && q1i == 0.0) continue;
            for(int k = 0; k < n2; ++k){
                double q2r = qre[1][k*n2 + lq], q2i = qim[1][k*n2 + lq];
                if(q2r == 0.0 && q2i == 0.0) continue;
                double ar = q1r*q2r - q1i*q2i;
                double ai = q1r*q2i + q1i*q2r;
                for(int n = 0; n < n3; ++n){
                    double cv = scg[(i*n2 + k)*n3 + n];
                    if(cv == 0.0) continue;
                    double q3r = qre[2][n*n3 + m];
                    double q3i = -qim[2][n*n3 + m];
                    acc += cv * (ar*q3r - ai*q3i);
                }
            }
        }
        val = acc;
    }

    red[t] = val * val;
    __syncthreads();
    if(t < 343) scg[t] = val;
    for(int s2 = 256; s2 > 0; s2 >>= 1){
        if(t < s2) red[t] += red[t + s2];
        __syncthreads();
    }
    const double scale = sqrt(2.0*j3 + 1.0) / sqrt(red[0]);

    for(int u = t; u < n1*n3*16; u += 512){
        int sl = u >> 4, jf = u & 15;
        int i  = sl / n3, k = sl - i*n3;
        int j  = jf - o2;
        double v2 = (j >= 0 && j < n2) ? scg[(i*n2 + j)*n3 + k] : 0.0;
        cgd2[(size_t)(TOFF[p] + sl)*16 + jf] = (float)(v2 * scale);
    }
}

// ---------------------------------------------------------------------------
// w prefetch / phase C templated on a compile-time path MASK.
// wreg packed densely by popcount of the mask prefix (<=5 entries per mask).
// ---------------------------------------------------------------------------
template<unsigned MASK>
__device__ __forceinline__ void prefetchW(const float* __restrict__ wbase,
                                          float* __restrict__ wreg)
{
    #pragma unroll
    for(int p = 0; p < NPATH; ++p){
        if((MASK >> p) & 1u)
            wreg[__builtin_popcount(MASK & ((1u << p) - 1u))] = wbase[POS[p]*NCHAN];
    }
}

template<unsigned MASK>
__device__ __forceinline__ void phaseC(const float* __restrict__ xr,
                                       const float* __restrict__ wreg,
                                       const float* __restrict__ Te,
                                       _Float16* __restrict__ ob)
{
    #pragma unroll
    for(int p = 0; p < NPATH; ++p){
        if(!((MASK >> p) & 1u)) continue;          // folds after unroll
        const int widx = __builtin_popcount(MASK & ((1u << p) - 1u));
        const int n1 = 2*L1[p] + 1;
        const int n3 = 2*L3[p] + 1;
        const int o1 = LOFF[L1[p]];
        const float wp = wreg[widx];
        const float* Tp = Te + TOFF[p];
        #pragma unroll
        for(int k = 0; k < n3; ++k){
            float acc = 0.f;
            #pragma unroll
            for(int i = 0; i < n1; ++i)
                acc = fmaf(xr[o1 + i], Tp[i*n3 + k], acc);
            ob[OOFF[p] + k] = (_Float16)(wp * acc);
        }
    }
}

// ---------------------------------------------------------------------------
// Main kernel (best structure, R15/R20, 251 us x2 runs): 4 edges/block,
// 512 threads (8 waves). Wave = (path group, edge half): grp = wid&3,
// el = (wid>>2)*2 + (lane>>5). One barrier sequence covers 4 edges. x issued
// after barrier 1 (hidden under phase B, not live across a barrier); <=5 w
// regs per wave; group 3 loads its 10 w values in two 5-value sub-phases.
// fp16 obuf staging + coalesced float4 flush (exact WRITE_SIZE).
// LDS ~32.6 KB + VGPR<=64 -> 4 blocks/CU = 32 waves/CU.
// ---------------------------------------------------------------------------
__global__ __launch_bounds__(NTHR, 8) void tp_main(
    const float* __restrict__ x, const float* __restrict__ y,
    const float* __restrict__ w, const float* __restrict__ cgd2,
    float* __restrict__ out)
{
    __shared__ __align__(16) _Float16 obuf[EPB*NCHAN*OUTW];  // 12672 h, 25.3 KB
    __shared__ float Ts[EPB*TTOT];                           // 1756 f, 7.0 KB
    __shared__ float ys[EPB*16];

    const int tid = threadIdx.x;
    const int e0  = blockIdx.x * EPB;

    const int lane = tid & 63;
    const int wid  = tid >> 6;
    const int c    = lane & 31;                 // channel
    const int grp  = wid & 3;                   // path group (0..3)
    const int el   = ((wid >> 2) << 1) | (lane >> 5);   // edge in block (0..3)
    const int e    = e0 + el;

    // prefetch this group's w values (<=5 registers, cheap to hold)
    const float* wbase = w + (size_t)e*NWROW + c;
    float wreg[5];
    switch(grp){
        case 0: prefetchW<G0M>(wbase, wreg); break;
        case 1: prefetchW<G1M>(wbase, wreg); break;
        case 2: prefetchW<G2M>(wbase, wreg); break;
        default: prefetchW<G3LO>(wbase, wreg); break;
    }

    if(tid < EPB*16) ys[tid] = y[e0*16 + tid];
    __syncthreads();                                   // barrier 1

    // issue x loads NOW — latency covered by phase B, consumed in phase C;
    // does not live across barrier 1 (register-pressure discipline, R14).
    const float4* xp = reinterpret_cast<const float4*>(x + (size_t)(e*NCHAN + c)*16);
    float4 x0 = xp[0], x1 = xp[1], x2 = xp[2], x3 = xp[3];

    // Phase B: T[el][s] = sum_j y[el][j] * cgd2[s][j]  (dense, 16 FMAs/slot)
    for(int u = tid; u < EPB*TTOT; u += NTHR){
        int eli = u / TTOT;
        int s   = u - eli*TTOT;
        const float* cr = cgd2 + (size_t)s*16;
        float acc = 0.f;
        #pragma unroll
        for(int j = 0; j < 16; ++j)
            acc = fmaf(ys[eli*16 + j], cr[j], acc);
        Ts[u] = acc;
    }
    __syncthreads();                                   // barrier 2

    // Phase C: straight-line per-wave path group
    float xr[16];
    xr[0]=x0.x;  xr[1]=x0.y;  xr[2]=x0.z;  xr[3]=x0.w;
    xr[4]=x1.x;  xr[5]=x1.y;  xr[6]=x1.z;  xr[7]=x1.w;
    xr[8]=x2.x;  xr[9]=x2.y;  xr[10]=x2.z; xr[11]=x2.w;
    xr[12]=x3.x; xr[13]=x3.y; xr[14]=x3.z; xr[15]=x3.w;

    const float* Te = Ts + el*TTOT;
    _Float16* ob = obuf + el*(NCHAN*OUTW) + c*OUTW;

    switch(grp){
        case 0: phaseC<G0M>(xr, wreg, Te, ob); break;
        case 1: phaseC<G1M>(xr, wreg, Te, ob); break;
        case 2: phaseC<G2M>(xr, wreg, Te, ob); break;
        default: {
            float wregB[5];
            prefetchW<G3HI>(wbase, wregB);      // issued early; waited on
            phaseC<G3LO>(xr, wreg, Te, ob);     //   under this compute
            phaseC<G3HI>(xr, wregB, Te, ob);
            break;
        }
    }
    __syncthreads();                                   // barrier 3

    // Flush: 12672 halfs -> coalesced float4 stores (exact WRITE_SIZE, proven)
    const h4* ob4 = reinterpret_cast<const h4*>(obuf);
    float4* o4 = reinterpret_cast<float4*>(out + (size_t)blockIdx.x * (EPB*NCHAN*OUTW));
    #pragma unroll
    for(int k2 = 0; k2 < 7; ++k2){
        int idx = tid + k2*NTHR;
        if(idx < EPB*NCHAN*OUTW/4){
            h4 hv = ob4[idx];
            float4 fv = { (float)hv[0], (float)hv[1], (float)hv[2], (float)hv[3] };
            o4[idx] = fv;
        }
    }
}

extern "C" void kernel_launch(void* const* d_in, const int* in_sizes, int n_in,
                              void* d_out, int out_size, void* d_ws, size_t ws_size,
                              hipStream_t stream)
{
    const float* x  = (const float*)d_in[0];
    const float* y  = (const float*)d_in[1];
    const float* wt = (const float*)d_in[2];
    float* out = (float*)d_out;
    float* cgd2 = (float*)d_ws;   // 439*16 floats = 28.1 KB of scratch

    cg_setup<<<NPATH, 512, 0, stream>>>(cgd2);
    tp_main<<<NBLK, NTHR, 0, stream>>>(x, y, wt, cgd2, out);
}